// Round 5
// baseline (229.200 us; speedup 1.0000x reference)
//
#include <hip/hip_runtime.h>
#include <hip/hip_bf16.h>

typedef unsigned short u16;
typedef unsigned int u32;
typedef short bf16x8 __attribute__((ext_vector_type(8)));
typedef float f32x4 __attribute__((ext_vector_type(4)));

#define NPX 32768

__device__ __forceinline__ u16 f2bf(float f) {
  union { float f; u32 u; } v; v.f = f;
  return (u16)((v.u + 0x7FFFu + ((v.u >> 16) & 1u)) >> 16);
}

// Coalesced B-operand layout: dst = kk*8192 + o*32 + lk*8 + e  (c = kk*32+lk*8+e)
// A wave's fragment load (16 lc x 4 lk x 16B) is then one contiguous burst.

// ---------------- prep kernels ----------------
__global__ __launch_bounds__(256) void prep_small(
    const float* __restrict__ wq, const float* __restrict__ wk,
    const float* __restrict__ wv, const float* __restrict__ w1,
    const float* __restrict__ wW, const float* __restrict__ gamma,
    const float* __restrict__ beta, const float* __restrict__ mean,
    const float* __restrict__ var,
    u16* __restrict__ wqb, u16* __restrict__ wkb, u16* __restrict__ wvb,
    u16* __restrict__ w1b, u16* __restrict__ wWpb, float* __restrict__ bWp) {
  int idx = blockIdx.x * 256 + threadIdx.x;
  if (idx < 65536) {
    int o = idx >> 8, c = idx & 255;
    int dst = (c >> 5) * 8192 + o * 32 + ((c >> 3) & 3) * 8 + (c & 7);
    wqb[dst] = f2bf(wq[idx]);
    wkb[dst] = f2bf(wk[idx]);
    wvb[dst] = f2bf(wv[idx]);
    w1b[dst] = f2bf(w1[idx]);
  } else if (idx < 65536 + 16384) {
    int j = idx - 65536;
    int o = j >> 6, c = j & 63;
    float inv = gamma[o] * rsqrtf(var[o] + 1e-5f);
    int dst = (c >> 5) * 8192 + o * 32 + ((c >> 3) & 3) * 8 + (c & 7);
    wWpb[dst] = f2bf(wW[j] * inv);
  } else if (idx < 65536 + 16384 + 256) {
    int o = idx - 65536 - 16384;
    float inv = gamma[o] * rsqrtf(var[o] + 1e-5f);
    bWp[o] = beta[o] - mean[o] * inv;
  }
}

// w3 [o][c][3][3] f32 -> w3c [tap][cb][ks][o][lk][8] bf16 (coalesced B-frag slabs)
__global__ __launch_bounds__(256) void prep_w3t(const float* __restrict__ w3,
                                                u16* __restrict__ w3c) {
  int idx = blockIdx.x * 256 + threadIdx.x;  // o*512+c, 131072 total
  int o = idx >> 9, c = idx & 511;
  int cb = c >> 6, ks = (c >> 5) & 1, lk = (c >> 3) & 3, e = c & 7;
  #pragma unroll
  for (int t = 0; t < 9; ++t)
    w3c[(size_t)(((t * 8 + cb) * 2 + ks) * 256 + o) * 32 + lk * 8 + e] =
        f2bf(w3[idx * 9 + t]);
}

// NCHW f32 -> [px][ch] bf16 (row stride `stride` channels, channel offset coff)
__global__ __launch_bounds__(256) void transpose_k(const float* __restrict__ src,
                                                   u16* __restrict__ dst,
                                                   int stride, int coff) {
  __shared__ u16 tile[64 * 72];
  int tid = threadIdx.x;
  int bid = blockIdx.x;
  int b = bid >> 8, rest = bid & 255;
  int c0 = (rest >> 6) * 64, px0 = (rest & 63) * 64;
  #pragma unroll
  for (int i = 0; i < 4; ++i) {
    int idx = tid + 256 * i;
    int c = idx >> 4, p4 = idx & 15;
    const float4 v = *(const float4*)&src[(size_t)(b * 256 + c0 + c) * 4096 + px0 + p4 * 4];
    u32 lo = f2bf(v.x) | ((u32)f2bf(v.y) << 16);
    u32 hi = f2bf(v.z) | ((u32)f2bf(v.w) << 16);
    *(uint2*)&tile[c * 72 + p4 * 4] = make_uint2(lo, hi);
  }
  __syncthreads();
  int px = tid >> 2, cq = tid & 3;
  u32 vv[8];
  #pragma unroll
  for (int i = 0; i < 8; ++i) {
    u16 a = tile[(cq * 16 + 2 * i) * 72 + px];
    u16 bb = tile[(cq * 16 + 2 * i + 1) * 72 + px];
    vv[i] = a | ((u32)bb << 16);
  }
  u16* dp = dst + (size_t)(b * 4096 + px0 + px) * stride + coff + c0 + cq * 16;
  *(uint4*)(dp) = make_uint4(vv[0], vv[1], vv[2], vv[3]);
  *(uint4*)(dp + 8) = make_uint4(vv[4], vv[5], vv[6], vv[7]);
}

// ---------------- shared GEMM helper: M=64 (LDS, swizzled), N=64*wave, K=256 ----------------
// Bg in coalesced layout: kk*8192 + n*32 + lk*8
__device__ __forceinline__ void gemm_k256(const u16* __restrict__ As,
                                          const u16* __restrict__ Bg,
                                          f32x4 acc[4][4], int lc, int lk, int wv_) {
  #pragma unroll
  for (int kk = 0; kk < 8; ++kk) {
    bf16x8 af[4], bfr[4];
    #pragma unroll
    for (int mi = 0; mi < 4; ++mi) {
      int px = mi * 16 + lc;
      int s = (kk * 4 + lk) ^ (px & 7);
      af[mi] = *(const bf16x8*)(As + px * 256 + s * 8);
    }
    #pragma unroll
    for (int nj = 0; nj < 4; ++nj) {
      int n = wv_ * 64 + nj * 16 + lc;
      bfr[nj] = *(const bf16x8*)(Bg + kk * 8192 + n * 32 + lk * 8);
    }
    #pragma unroll
    for (int mi = 0; mi < 4; ++mi)
      #pragma unroll
      for (int nj = 0; nj < 4; ++nj)
        acc[mi][nj] = __builtin_amdgcn_mfma_f32_16x16x32_bf16(af[mi], bfr[nj], acc[mi][nj], 0, 0, 0);
  }
}

// ---------------- pass 1: fused QKV + attention + W*weighted + BN ----------------
__global__ __launch_bounds__(256, 2) void attn_kernel(
    const u16* __restrict__ xq, u16* __restrict__ xcat,
    const u16* __restrict__ wqb, const u16* __restrict__ wkb, const u16* __restrict__ wvb,
    const float* __restrict__ bq, const float* __restrict__ bk, const float* __restrict__ bv,
    const u16* __restrict__ wWpb, const float* __restrict__ bWp) {
  __shared__ __align__(16) char smem[74752];
  u16* aq = (u16*)smem;                    // [64][256] swizzled, 32KB
  u16* ak = (u16*)(smem + 32768);          // [64][256] swizzled, 32KB
  float* att_s = (float*)(smem + 65536);   // [4][64]
  u16* wsum = (u16*)(smem + 66560);        // [64][64] swizzled, 8KB
  float* wbuf = (float*)smem;              // [4][64][64] f32, reuses aq/ak

  int tid = threadIdx.x;
  int lane = tid & 63, wv_ = tid >> 6;
  int lc = lane & 15, lk = lane >> 4;
  int px0 = blockIdx.x * 64;

  #pragma unroll
  for (int i = 0; i < 8; ++i) {
    int idx = tid + 256 * i;
    int px = idx >> 5, c = idx & 31;
    int sc = c ^ (px & 7);
    *(uint4*)(aq + px * 256 + sc * 8) = *(const uint4*)(xq + (size_t)(px0 + px) * 256 + c * 8);
    *(uint4*)(ak + px * 256 + sc * 8) = *(const uint4*)(xcat + (size_t)(px0 + px) * 512 + c * 8);
  }
  __syncthreads();

  f32x4 zero4 = {0.f, 0.f, 0.f, 0.f};
  f32x4 accq[4][4], acck[4][4];
  #pragma unroll
  for (int mi = 0; mi < 4; ++mi)
    #pragma unroll
    for (int nj = 0; nj < 4; ++nj) { accq[mi][nj] = zero4; acck[mi][nj] = zero4; }

  gemm_k256(aq, wqb, accq, lc, lk, wv_);
  gemm_k256(ak, wkb, acck, lc, lk, wv_);

  #pragma unroll
  for (int nj = 0; nj < 4; ++nj) {
    float bqv = bq[wv_ * 64 + nj * 16 + lc];
    float bkv = bk[wv_ * 64 + nj * 16 + lc];
    #pragma unroll
    for (int mi = 0; mi < 4; ++mi)
      #pragma unroll
      for (int j = 0; j < 4; ++j) { accq[mi][nj][j] += bqv; acck[mi][nj][j] += bkv; }
  }

  // attention scores for own head (wave == head); reduce over the 16 col-lanes
  float smx[4][4];
  #pragma unroll
  for (int mi = 0; mi < 4; ++mi)
    #pragma unroll
    for (int j = 0; j < 4; ++j) {
      float p = 0.f;
      #pragma unroll
      for (int nj = 0; nj < 4; ++nj) p += accq[mi][nj][j] * acck[mi][nj][j];
      p += __shfl_xor(p, 1);
      p += __shfl_xor(p, 2);
      p += __shfl_xor(p, 4);
      p += __shfl_xor(p, 8);
      float a = p * 0.0625f;  // / sqrt(256)
      smx[mi][j] = a;
      if (lc == 0) att_s[wv_ * 64 + mi * 16 + lk * 4 + j] = a;
    }
  __syncthreads();
  // softmax over 4 heads
  #pragma unroll
  for (int mi = 0; mi < 4; ++mi)
    #pragma unroll
    for (int j = 0; j < 4; ++j) {
      int px = mi * 16 + lk * 4 + j;
      float a0 = att_s[px], a1 = att_s[64 + px], a2 = att_s[128 + px], a3 = att_s[192 + px];
      float mx = fmaxf(fmaxf(a0, a1), fmaxf(a2, a3));
      float e0 = __expf(a0 - mx), e1 = __expf(a1 - mx);
      float e2 = __expf(a2 - mx), e3 = __expf(a3 - mx);
      float den = e0 + e1 + e2 + e3;
      float ew = wv_ == 0 ? e0 : (wv_ == 1 ? e1 : (wv_ == 2 ? e2 : e3));
      smx[mi][j] = ew / den;
    }

  // V projection
  f32x4 accv[4][4];
  #pragma unroll
  for (int mi = 0; mi < 4; ++mi)
    #pragma unroll
    for (int nj = 0; nj < 4; ++nj) accv[mi][nj] = zero4;
  gemm_k256(ak, wvb, accv, lc, lk, wv_);
  #pragma unroll
  for (int nj = 0; nj < 4; ++nj) {
    float bvv = bv[wv_ * 64 + nj * 16 + lc];
    #pragma unroll
    for (int mi = 0; mi < 4; ++mi)
      #pragma unroll
      for (int j = 0; j < 4; ++j) accv[mi][nj][j] += bvv;
  }
  __syncthreads();  // all waves done reading aq/ak -> reuse as wbuf

  #pragma unroll
  for (int mi = 0; mi < 4; ++mi)
    #pragma unroll
    for (int nj = 0; nj < 4; ++nj)
      #pragma unroll
      for (int j = 0; j < 4; ++j) {
        int px = mi * 16 + lk * 4 + j;
        wbuf[(wv_ * 64 + px) * 64 + nj * 16 + lc] = smx[mi][j] * accv[mi][nj][j];
      }
  __syncthreads();

  // sum heads -> weighted [64px][64d] bf16 (swizzled)
  #pragma unroll
  for (int i = 0; i < 2; ++i) {
    int idx = tid + 256 * i;
    int px = idx >> 3, c = idx & 7;
    float a8[8] = {0.f, 0.f, 0.f, 0.f, 0.f, 0.f, 0.f, 0.f};
    #pragma unroll
    for (int h = 0; h < 4; ++h) {
      const float4* p = (const float4*)(wbuf + ((h * 64 + px) * 64 + c * 8));
      float4 u0 = p[0], u1 = p[1];
      a8[0] += u0.x; a8[1] += u0.y; a8[2] += u0.z; a8[3] += u0.w;
      a8[4] += u1.x; a8[5] += u1.y; a8[6] += u1.z; a8[7] += u1.w;
    }
    u32 p0 = f2bf(a8[0]) | ((u32)f2bf(a8[1]) << 16);
    u32 p1 = f2bf(a8[2]) | ((u32)f2bf(a8[3]) << 16);
    u32 p2 = f2bf(a8[4]) | ((u32)f2bf(a8[5]) << 16);
    u32 p3 = f2bf(a8[6]) | ((u32)f2bf(a8[7]) << 16);
    *(uint4*)(wsum + px * 64 + (c ^ (px & 7)) * 8) = make_uint4(p0, p1, p2, p3);
  }
  __syncthreads();

  // out = weighted x wW'^T + bWp  (K=64, coalesced layout: kk*8192 + n*32 + lk*8)
  f32x4 a4[4][4];
  #pragma unroll
  for (int mi = 0; mi < 4; ++mi)
    #pragma unroll
    for (int nj = 0; nj < 4; ++nj) a4[mi][nj] = zero4;
  #pragma unroll
  for (int kk = 0; kk < 2; ++kk) {
    bf16x8 af[4], bfr[4];
    #pragma unroll
    for (int mi = 0; mi < 4; ++mi) {
      int px = mi * 16 + lc;
      int s = (kk * 4 + lk) ^ (px & 7);
      af[mi] = *(const bf16x8*)(wsum + px * 64 + s * 8);
    }
    #pragma unroll
    for (int nj = 0; nj < 4; ++nj) {
      int n = wv_ * 64 + nj * 16 + lc;
      bfr[nj] = *(const bf16x8*)(wWpb + kk * 8192 + n * 32 + lk * 8);
    }
    #pragma unroll
    for (int mi = 0; mi < 4; ++mi)
      #pragma unroll
      for (int nj = 0; nj < 4; ++nj)
        a4[mi][nj] = __builtin_amdgcn_mfma_f32_16x16x32_bf16(af[mi], bfr[nj], a4[mi][nj], 0, 0, 0);
  }
  #pragma unroll
  for (int nj = 0; nj < 4; ++nj) {
    int o = wv_ * 64 + nj * 16 + lc;
    float bb = bWp[o];
    #pragma unroll
    for (int mi = 0; mi < 4; ++mi)
      #pragma unroll
      for (int j = 0; j < 4; ++j) {
        int px = mi * 16 + lk * 4 + j;
        xcat[(size_t)(px0 + px) * 512 + 256 + o] = f2bf(a4[mi][nj][j] + bb);
      }
  }
}

// ---------------- pass 2: reflect-pad 3x3 conv (512->256) + ELU ----------------
// M=32 px strips, grid 1024 -> 4 blocks/CU (16 waves/CU). 256 thr = 4 waves,
// each wave a distinct 64-wide n slice (no cross-wave weight duplication
// within a block). LDS: double-buffered 3row x 36px x 64ch tile (27.6 KB).
// Lean VGPR (~115, enforced <=128): acc[2][4]=32 + stage 16 + frags 24.
__global__ __launch_bounds__(256, 4) void conv3_kernel(
    const u16* __restrict__ xcat, const u16* __restrict__ w3c,
    const float* __restrict__ b3, u16* __restrict__ elux) {
  __shared__ __align__(16) u16 xt[2][3 * 36 * 64];  // 2 x 13824 B
  int tid = threadIdx.x;
  int lane = tid & 63, wv_ = tid >> 6;
  int lc = lane & 15, lk = lane >> 4;
  int bid = blockIdx.x;
  int b = bid >> 7, rest = bid & 127;
  int r = rest >> 1, h = rest & 1;
  int w0 = h * 32;

  // staging: 816 chunks (3 rows x 34 px x 8 slots), 4 per thread
  int ldsoff[4], goff[4];
  bool valid[4];
  #pragma unroll
  for (int i = 0; i < 4; ++i) {
    int idx = tid + 256 * i;
    valid[i] = idx < 816;
    int ci = valid[i] ? idx : 815;
    int row = ci / 272, rem = ci - row * 272;
    int pxr = rem >> 3, t = rem & 7;
    int h_in = r - 1 + row; h_in = h_in < 0 ? 1 : (h_in > 63 ? 62 : h_in);
    int w_in = w0 - 1 + pxr; w_in = w_in < 0 ? 1 : (w_in > 63 ? 62 : w_in);
    ldsoff[i] = (row * 36 + pxr) * 64 + t * 8;
    goff[i] = ((b * 64 + h_in) * 64 + w_in) * 512 + (t ^ (pxr & 7)) * 8;
  }

  f32x4 zero4 = {0.f, 0.f, 0.f, 0.f};
  f32x4 acc[2][4];
  #pragma unroll
  for (int mi = 0; mi < 2; ++mi)
    #pragma unroll
    for (int nj = 0; nj < 4; ++nj) acc[mi][nj] = zero4;

  uint4 stA[4], stB[4];
  #pragma unroll
  for (int i = 0; i < 4; ++i)
    if (valid[i]) stA[i] = *(const uint4*)(xcat + goff[i]);
  #pragma unroll
  for (int i = 0; i < 4; ++i)
    if (valid[i]) *(uint4*)(xt[0] + ldsoff[i]) = stA[i];
  __syncthreads();

#define CONV_PHASE(CB, CUR, NXT)                                                 \
  do {                                                                           \
    if ((CB) < 7) {                                                              \
      _Pragma("unroll") for (int i = 0; i < 4; ++i)                              \
          if (valid[i]) NXT[i] = *(const uint4*)(xcat + goff[i] + ((CB) + 1) * 64); \
    }                                                                            \
    const u16* xb = xt[(CUR)];                                                   \
    _Pragma("unroll") for (int dy = 0; dy < 3; ++dy)                             \
      _Pragma("unroll") for (int dx = 0; dx < 3; ++dx) {                         \
        const u16* wt = w3c + (size_t)(((dy * 3 + dx) * 8 + (CB)) * 2) * 8192;   \
        _Pragma("unroll") for (int ks = 0; ks < 2; ++ks) {                       \
          bf16x8 af[2], bfr[4];                                                  \
          _Pragma("unroll") for (int nj = 0; nj < 4; ++nj)                       \
            bfr[nj] = *(const bf16x8*)(wt + ks * 8192 +                          \
                                       (wv_ * 64 + nj * 16 + lc) * 32 + lk * 8); \
          _Pragma("unroll") for (int mi = 0; mi < 2; ++mi) {                     \
            int pp = mi * 16 + lc + dx;                                          \
            int s = (ks * 4 + lk) ^ (pp & 7);                                    \
            af[mi] = *(const bf16x8*)(xb + (dy * 36 + pp) * 64 + s * 8);         \
          }                                                                      \
          _Pragma("unroll") for (int mi = 0; mi < 2; ++mi)                       \
            _Pragma("unroll") for (int nj = 0; nj < 4; ++nj)                     \
              acc[mi][nj] = __builtin_amdgcn_mfma_f32_16x16x32_bf16(             \
                  af[mi], bfr[nj], acc[mi][nj], 0, 0, 0);                        \
        }                                                                        \
      }                                                                          \
    if ((CB) < 7) {                                                              \
      _Pragma("unroll") for (int i = 0; i < 4; ++i)                              \
          if (valid[i]) *(uint4*)(xt[(CUR) ^ 1] + ldsoff[i]) = NXT[i];           \
      __syncthreads();                                                           \
    }                                                                            \
  } while (0)

  CONV_PHASE(0, 0, stB);
  CONV_PHASE(1, 1, stA);
  CONV_PHASE(2, 0, stB);
  CONV_PHASE(3, 1, stA);
  CONV_PHASE(4, 0, stB);
  CONV_PHASE(5, 1, stA);
  CONV_PHASE(6, 0, stB);
  CONV_PHASE(7, 1, stA);
#undef CONV_PHASE

  size_t pxb = (size_t)(b * 64 + r) * 64 + w0;
  #pragma unroll
  for (int nj = 0; nj < 4; ++nj) {
    int o = wv_ * 64 + nj * 16 + lc;
    float bias = b3[o];
    #pragma unroll
    for (int mi = 0; mi < 2; ++mi)
      #pragma unroll
      for (int j = 0; j < 4; ++j) {
        int p = mi * 16 + lk * 4 + j;
        float v = acc[mi][nj][j] + bias;
        v = v > 0.f ? v : (__expf(v) - 1.f);  // ELU
        elux[(pxb + p) * 256 + o] = f2bf(v);
      }
  }
}

// ---------------- pass 3: final 1x1 conv -> f32 NCHW ----------------
__global__ __launch_bounds__(256, 3) void final_kernel(
    const u16* __restrict__ elux, const u16* __restrict__ w1b,
    const float* __restrict__ b1, float* __restrict__ out) {
  __shared__ __align__(16) u16 at[64 * 256];
  int tid = threadIdx.x;
  int lane = tid & 63, wv_ = tid >> 6;
  int lc = lane & 15, lk = lane >> 4;
  int px0 = blockIdx.x * 64;
  #pragma unroll
  for (int i = 0; i < 8; ++i) {
    int idx = tid + 256 * i;
    int px = idx >> 5, c = idx & 31;
    *(uint4*)(at + px * 256 + (c ^ (px & 7)) * 8) =
        *(const uint4*)(elux + (size_t)(px0 + px) * 256 + c * 8);
  }
  __syncthreads();
  f32x4 zero4 = {0.f, 0.f, 0.f, 0.f};
  f32x4 acc[4][4];
  #pragma unroll
  for (int mi = 0; mi < 4; ++mi)
    #pragma unroll
    for (int nj = 0; nj < 4; ++nj) acc[mi][nj] = zero4;
  gemm_k256(at, w1b, acc, lc, lk, wv_);
  int b = px0 >> 12;
  int hw0 = px0 & 4095;
  #pragma unroll
  for (int nj = 0; nj < 4; ++nj) {
    int o = wv_ * 64 + nj * 16 + lc;
    float bias = b1[o];
    #pragma unroll
    for (int mi = 0; mi < 4; ++mi) {
      float4 v;
      v.x = acc[mi][nj][0] + bias;
      v.y = acc[mi][nj][1] + bias;
      v.z = acc[mi][nj][2] + bias;
      v.w = acc[mi][nj][3] + bias;
      *(float4*)&out[(size_t)(b * 256 + o) * 4096 + hw0 + mi * 16 + lk * 4] = v;
    }
  }
}

extern "C" void kernel_launch(void* const* d_in, const int* in_sizes, int n_in,
                              void* d_out, int out_size, void* d_ws, size_t ws_size,
                              hipStream_t stream) {
  const float* key   = (const float*)d_in[0];
  const float* query = (const float*)d_in[1];
  const float* wq    = (const float*)d_in[2];
  const float* bq    = (const float*)d_in[3];
  const float* wk    = (const float*)d_in[4];
  const float* bk    = (const float*)d_in[5];
  const float* wv    = (const float*)d_in[6];
  const float* bv    = (const float*)d_in[7];
  const float* wW    = (const float*)d_in[8];
  const float* gamma = (const float*)d_in[9];
  const float* beta  = (const float*)d_in[10];
  const float* mean  = (const float*)d_in[11];
  const float* var   = (const float*)d_in[12];
  const float* w3    = (const float*)d_in[13];
  const float* b3    = (const float*)d_in[14];
  const float* w1    = (const float*)d_in[15];
  const float* b1    = (const float*)d_in[16];
  float* out = (float*)d_out;

  char* ws = (char*)d_ws;
  u16* x_q   = (u16*)(ws);                    // 16,777,216 B  [NPX][256] bf16 (query NHWC)
  u16* xcat  = (u16*)(ws + 16777216);         // 33,554,432 B  [NPX][512] bf16 (key | attn out)
  u16* elux  = (u16*)(ws + 50331648);         // 16,777,216 B  [NPX][256] bf16
  u16* w3t   = (u16*)(ws + 67108864);         //  2,359,296 B  [9][8][2][256][32] bf16
  u16* wqb   = (u16*)(ws + 69468160);         //    131,072 B
  u16* wkb   = (u16*)(ws + 69599232);
  u16* wvb   = (u16*)(ws + 69730304);
  u16* w1b   = (u16*)(ws + 69861376);
  u16* wWpb  = (u16*)(ws + 69992448);         //     32,768 B
  float* bWp = (float*)(ws + 70025216);       //      1,024 B

  prep_small<<<321, 256, 0, stream>>>(wq, wk, wv, w1, wW, gamma, beta, mean, var,
                                      wqb, wkb, wvb, w1b, wWpb, bWp);
  prep_w3t<<<512, 256, 0, stream>>>(w3, w3t);
  transpose_k<<<2048, 256, 0, stream>>>(query, x_q, 256, 0);
  transpose_k<<<2048, 256, 0, stream>>>(key, xcat, 512, 0);
  attn_kernel<<<512, 256, 0, stream>>>(x_q, xcat, wqb, wkb, wvb, bq, bk, bv, wWpb, bWp);
  conv3_kernel<<<1024, 256, 0, stream>>>(xcat, w3t, b3, elux);
  final_kernel<<<512, 256, 0, stream>>>(elux, w1b, b1, out);
}

// Round 6
// 136.199 us; speedup vs baseline: 1.6828x; 1.6828x over previous
//
#include <hip/hip_runtime.h>
#include <hip/hip_bf16.h>

typedef unsigned short u16;
typedef unsigned int u32;
typedef short bf16x8 __attribute__((ext_vector_type(8)));
typedef float f32x4 __attribute__((ext_vector_type(4)));

#define NPX 32768

__device__ __forceinline__ u16 f2bf(float f) {
  union { float f; u32 u; } v; v.f = f;
  return (u16)((v.u + 0x7FFFu + ((v.u >> 16) & 1u)) >> 16);
}

__device__ __forceinline__ void gload16(const u16* g, u16* l) {
  __builtin_amdgcn_global_load_lds(
      (const __attribute__((address_space(1))) void*)g,
      (__attribute__((address_space(3))) void*)l, 16, 0, 0);
}

// Coalesced B-operand layout: dst = kk*8192 + o*32 + lk*8 + e  (c = kk*32+lk*8+e)

// ---------------- prep kernels ----------------
__global__ __launch_bounds__(256) void prep_small(
    const float* __restrict__ wq, const float* __restrict__ wk,
    const float* __restrict__ wv, const float* __restrict__ w1,
    const float* __restrict__ wW, const float* __restrict__ gamma,
    const float* __restrict__ beta, const float* __restrict__ mean,
    const float* __restrict__ var,
    u16* __restrict__ wqb, u16* __restrict__ wkb, u16* __restrict__ wvb,
    u16* __restrict__ w1b, u16* __restrict__ wWpb, float* __restrict__ bWp) {
  int idx = blockIdx.x * 256 + threadIdx.x;
  if (idx < 65536) {
    int o = idx >> 8, c = idx & 255;
    int dst = (c >> 5) * 8192 + o * 32 + ((c >> 3) & 3) * 8 + (c & 7);
    wqb[dst] = f2bf(wq[idx]);
    wkb[dst] = f2bf(wk[idx]);
    wvb[dst] = f2bf(wv[idx]);
    w1b[dst] = f2bf(w1[idx]);
  } else if (idx < 65536 + 16384) {
    int j = idx - 65536;
    int o = j >> 6, c = j & 63;
    float inv = gamma[o] * rsqrtf(var[o] + 1e-5f);
    int dst = (c >> 5) * 8192 + o * 32 + ((c >> 3) & 3) * 8 + (c & 7);
    wWpb[dst] = f2bf(wW[j] * inv);
  } else if (idx < 65536 + 16384 + 256) {
    int o = idx - 65536 - 16384;
    float inv = gamma[o] * rsqrtf(var[o] + 1e-5f);
    bWp[o] = beta[o] - mean[o] * inv;
  }
}

// w3 [o][c][3][3] f32 -> w3c [(t*8+cb)][ks][o][lk][8] bf16 slabs (16384 u16 per (t,cb))
__global__ __launch_bounds__(256) void prep_w3t(const float* __restrict__ w3,
                                                u16* __restrict__ w3c) {
  int idx = blockIdx.x * 256 + threadIdx.x;  // o*512+c, 131072 total
  int o = idx >> 9, c = idx & 511;
  int cb = c >> 6, ks = (c >> 5) & 1, lk = (c >> 3) & 3, e = c & 7;
  #pragma unroll
  for (int t = 0; t < 9; ++t)
    w3c[(size_t)(((t * 8 + cb) * 2 + ks) * 256 + o) * 32 + lk * 8 + e] =
        f2bf(w3[idx * 9 + t]);
}

// NCHW f32 -> [px][ch] bf16 (row stride `stride` channels, channel offset coff)
__global__ __launch_bounds__(256) void transpose_k(const float* __restrict__ src,
                                                   u16* __restrict__ dst,
                                                   int stride, int coff) {
  __shared__ u16 tile[64 * 72];
  int tid = threadIdx.x;
  int bid = blockIdx.x;
  int b = bid >> 8, rest = bid & 255;
  int c0 = (rest >> 6) * 64, px0 = (rest & 63) * 64;
  #pragma unroll
  for (int i = 0; i < 4; ++i) {
    int idx = tid + 256 * i;
    int c = idx >> 4, p4 = idx & 15;
    const float4 v = *(const float4*)&src[(size_t)(b * 256 + c0 + c) * 4096 + px0 + p4 * 4];
    u32 lo = f2bf(v.x) | ((u32)f2bf(v.y) << 16);
    u32 hi = f2bf(v.z) | ((u32)f2bf(v.w) << 16);
    *(uint2*)&tile[c * 72 + p4 * 4] = make_uint2(lo, hi);
  }
  __syncthreads();
  int px = tid >> 2, cq = tid & 3;
  u32 vv[8];
  #pragma unroll
  for (int i = 0; i < 8; ++i) {
    u16 a = tile[(cq * 16 + 2 * i) * 72 + px];
    u16 bb = tile[(cq * 16 + 2 * i + 1) * 72 + px];
    vv[i] = a | ((u32)bb << 16);
  }
  u16* dp = dst + (size_t)(b * 4096 + px0 + px) * stride + coff + c0 + cq * 16;
  *(uint4*)(dp) = make_uint4(vv[0], vv[1], vv[2], vv[3]);
  *(uint4*)(dp + 8) = make_uint4(vv[4], vv[5], vv[6], vv[7]);
}

// ---------------- shared GEMM helper: M=64 (LDS, swizzled), N=64*wave, K=256 ----------------
__device__ __forceinline__ void gemm_k256(const u16* __restrict__ As,
                                          const u16* __restrict__ Bg,
                                          f32x4 acc[4][4], int lc, int lk, int wv_) {
  #pragma unroll
  for (int kk = 0; kk < 8; ++kk) {
    bf16x8 af[4], bfr[4];
    #pragma unroll
    for (int mi = 0; mi < 4; ++mi) {
      int px = mi * 16 + lc;
      int s = (kk * 4 + lk) ^ (px & 7);
      af[mi] = *(const bf16x8*)(As + px * 256 + s * 8);
    }
    #pragma unroll
    for (int nj = 0; nj < 4; ++nj) {
      int n = wv_ * 64 + nj * 16 + lc;
      bfr[nj] = *(const bf16x8*)(Bg + kk * 8192 + n * 32 + lk * 8);
    }
    #pragma unroll
    for (int mi = 0; mi < 4; ++mi)
      #pragma unroll
      for (int nj = 0; nj < 4; ++nj)
        acc[mi][nj] = __builtin_amdgcn_mfma_f32_16x16x32_bf16(af[mi], bfr[nj], acc[mi][nj], 0, 0, 0);
  }
}

// ---------------- pass 1: fused QKV + attention + W*weighted + BN ----------------
__global__ __launch_bounds__(256, 2) void attn_kernel(
    const u16* __restrict__ xq, u16* __restrict__ xcat,
    const u16* __restrict__ wqb, const u16* __restrict__ wkb, const u16* __restrict__ wvb,
    const float* __restrict__ bq, const float* __restrict__ bk, const float* __restrict__ bv,
    const u16* __restrict__ wWpb, const float* __restrict__ bWp) {
  __shared__ __align__(16) char smem[74752];
  u16* aq = (u16*)smem;                    // [64][256] swizzled, 32KB
  u16* ak = (u16*)(smem + 32768);          // [64][256] swizzled, 32KB
  float* att_s = (float*)(smem + 65536);   // [4][64]
  u16* wsum = (u16*)(smem + 66560);        // [64][64] swizzled, 8KB
  float* wbuf = (float*)smem;              // [4][64][64] f32, reuses aq/ak

  int tid = threadIdx.x;
  int lane = tid & 63, wv_ = tid >> 6;
  int lc = lane & 15, lk = lane >> 4;
  int px0 = blockIdx.x * 64;

  #pragma unroll
  for (int i = 0; i < 8; ++i) {
    int idx = tid + 256 * i;
    int px = idx >> 5, c = idx & 31;
    int sc = c ^ (px & 7);
    *(uint4*)(aq + px * 256 + sc * 8) = *(const uint4*)(xq + (size_t)(px0 + px) * 256 + c * 8);
    *(uint4*)(ak + px * 256 + sc * 8) = *(const uint4*)(xcat + (size_t)(px0 + px) * 512 + c * 8);
  }
  __syncthreads();

  f32x4 zero4 = {0.f, 0.f, 0.f, 0.f};
  f32x4 accq[4][4], acck[4][4];
  #pragma unroll
  for (int mi = 0; mi < 4; ++mi)
    #pragma unroll
    for (int nj = 0; nj < 4; ++nj) { accq[mi][nj] = zero4; acck[mi][nj] = zero4; }

  gemm_k256(aq, wqb, accq, lc, lk, wv_);
  gemm_k256(ak, wkb, acck, lc, lk, wv_);

  #pragma unroll
  for (int nj = 0; nj < 4; ++nj) {
    float bqv = bq[wv_ * 64 + nj * 16 + lc];
    float bkv = bk[wv_ * 64 + nj * 16 + lc];
    #pragma unroll
    for (int mi = 0; mi < 4; ++mi)
      #pragma unroll
      for (int j = 0; j < 4; ++j) { accq[mi][nj][j] += bqv; acck[mi][nj][j] += bkv; }
  }

  // attention scores for own head (wave == head); reduce over the 16 col-lanes
  float smx[4][4];
  #pragma unroll
  for (int mi = 0; mi < 4; ++mi)
    #pragma unroll
    for (int j = 0; j < 4; ++j) {
      float p = 0.f;
      #pragma unroll
      for (int nj = 0; nj < 4; ++nj) p += accq[mi][nj][j] * acck[mi][nj][j];
      p += __shfl_xor(p, 1);
      p += __shfl_xor(p, 2);
      p += __shfl_xor(p, 4);
      p += __shfl_xor(p, 8);
      float a = p * 0.0625f;  // / sqrt(256)
      smx[mi][j] = a;
      if (lc == 0) att_s[wv_ * 64 + mi * 16 + lk * 4 + j] = a;
    }
  __syncthreads();
  // softmax over 4 heads
  #pragma unroll
  for (int mi = 0; mi < 4; ++mi)
    #pragma unroll
    for (int j = 0; j < 4; ++j) {
      int px = mi * 16 + lk * 4 + j;
      float a0 = att_s[px], a1 = att_s[64 + px], a2 = att_s[128 + px], a3 = att_s[192 + px];
      float mx = fmaxf(fmaxf(a0, a1), fmaxf(a2, a3));
      float e0 = __expf(a0 - mx), e1 = __expf(a1 - mx);
      float e2 = __expf(a2 - mx), e3 = __expf(a3 - mx);
      float den = e0 + e1 + e2 + e3;
      float ew = wv_ == 0 ? e0 : (wv_ == 1 ? e1 : (wv_ == 2 ? e2 : e3));
      smx[mi][j] = ew / den;
    }

  // V projection
  f32x4 accv[4][4];
  #pragma unroll
  for (int mi = 0; mi < 4; ++mi)
    #pragma unroll
    for (int nj = 0; nj < 4; ++nj) accv[mi][nj] = zero4;
  gemm_k256(ak, wvb, accv, lc, lk, wv_);
  #pragma unroll
  for (int nj = 0; nj < 4; ++nj) {
    float bvv = bv[wv_ * 64 + nj * 16 + lc];
    #pragma unroll
    for (int mi = 0; mi < 4; ++mi)
      #pragma unroll
      for (int j = 0; j < 4; ++j) accv[mi][nj][j] += bvv;
  }
  __syncthreads();  // all waves done reading aq/ak -> reuse as wbuf

  #pragma unroll
  for (int mi = 0; mi < 4; ++mi)
    #pragma unroll
    for (int nj = 0; nj < 4; ++nj)
      #pragma unroll
      for (int j = 0; j < 4; ++j) {
        int px = mi * 16 + lk * 4 + j;
        wbuf[(wv_ * 64 + px) * 64 + nj * 16 + lc] = smx[mi][j] * accv[mi][nj][j];
      }
  __syncthreads();

  // sum heads -> weighted [64px][64d] bf16 (swizzled)
  #pragma unroll
  for (int i = 0; i < 2; ++i) {
    int idx = tid + 256 * i;
    int px = idx >> 3, c = idx & 7;
    float a8[8] = {0.f, 0.f, 0.f, 0.f, 0.f, 0.f, 0.f, 0.f};
    #pragma unroll
    for (int h = 0; h < 4; ++h) {
      const float4* p = (const float4*)(wbuf + ((h * 64 + px) * 64 + c * 8));
      float4 u0 = p[0], u1 = p[1];
      a8[0] += u0.x; a8[1] += u0.y; a8[2] += u0.z; a8[3] += u0.w;
      a8[4] += u1.x; a8[5] += u1.y; a8[6] += u1.z; a8[7] += u1.w;
    }
    u32 p0 = f2bf(a8[0]) | ((u32)f2bf(a8[1]) << 16);
    u32 p1 = f2bf(a8[2]) | ((u32)f2bf(a8[3]) << 16);
    u32 p2 = f2bf(a8[4]) | ((u32)f2bf(a8[5]) << 16);
    u32 p3 = f2bf(a8[6]) | ((u32)f2bf(a8[7]) << 16);
    *(uint4*)(wsum + px * 64 + (c ^ (px & 7)) * 8) = make_uint4(p0, p1, p2, p3);
  }
  __syncthreads();

  // out = weighted x wW'^T + bWp  (K=64, coalesced layout: kk*8192 + n*32 + lk*8)
  f32x4 a4[4][4];
  #pragma unroll
  for (int mi = 0; mi < 4; ++mi)
    #pragma unroll
    for (int nj = 0; nj < 4; ++nj) a4[mi][nj] = zero4;
  #pragma unroll
  for (int kk = 0; kk < 2; ++kk) {
    bf16x8 af[4], bfr[4];
    #pragma unroll
    for (int mi = 0; mi < 4; ++mi) {
      int px = mi * 16 + lc;
      int s = (kk * 4 + lk) ^ (px & 7);
      af[mi] = *(const bf16x8*)(wsum + px * 64 + s * 8);
    }
    #pragma unroll
    for (int nj = 0; nj < 4; ++nj) {
      int n = wv_ * 64 + nj * 16 + lc;
      bfr[nj] = *(const bf16x8*)(wWpb + kk * 8192 + n * 32 + lk * 8);
    }
    #pragma unroll
    for (int mi = 0; mi < 4; ++mi)
      #pragma unroll
      for (int nj = 0; nj < 4; ++nj)
        a4[mi][nj] = __builtin_amdgcn_mfma_f32_16x16x32_bf16(af[mi], bfr[nj], a4[mi][nj], 0, 0, 0);
  }
  #pragma unroll
  for (int nj = 0; nj < 4; ++nj) {
    int o = wv_ * 64 + nj * 16 + lc;
    float bb = bWp[o];
    #pragma unroll
    for (int mi = 0; mi < 4; ++mi)
      #pragma unroll
      for (int j = 0; j < 4; ++j) {
        int px = mi * 16 + lk * 4 + j;
        xcat[(size_t)(px0 + px) * 512 + 256 + o] = f2bf(a4[mi][nj][j] + bb);
      }
  }
}

// ---------------- pass 2: reflect-pad 3x3 conv (512->256) + ELU ----------------
// Canonical 2-phase LDS GEMM: M=128 (2 rows), N=256, 72 phases of K=64
// ((cb,tap) pairs). BOTH operands staged via global_load_lds, double-buffered;
// no global->VGPR loads inside the loop. Grid 256 = 1 block/CU. 8 waves 2Mx4N.
// W-LDS chunk-swizzle p = j ^ ((j>>3)&7) applied on source AND read (rule #21).
__global__ __launch_bounds__(512, 2) void conv3_kernel(
    const u16* __restrict__ xcat, const u16* __restrict__ w3c,
    const float* __restrict__ b3, u16* __restrict__ elux) {
  extern __shared__ __align__(16) u16 smem[];
  u16* xb0 = smem;              // [4][66][64] = 16896 u16
  u16* xb1 = smem + 16896;
  u16* wb0 = smem + 33792;      // [2ks][256n][32] = 16384 u16
  u16* wb1 = smem + 50176;      // total 66560 u16 = 133120 B

  int tid = threadIdx.x;
  int lane = tid & 63, wave = tid >> 6;
  int lc = lane & 15, lk = lane >> 4;
  int wr = wave >> 2, wc = wave & 3;
  int b = blockIdx.x >> 5, r0 = (blockIdx.x & 31) * 2;

  // x staging source offsets: 2112 chunks = 4 rows x 66 px x 8; 4/thread + 64 tail
  int gx[4], gxt;
  #pragma unroll
  for (int i = 0; i < 5; ++i) {
    int idx = (i < 4) ? (tid + i * 512) : (2048 + lane);
    int px = idx >> 3, t = idx & 7;
    int row = px / 66;
    int pxr = px - row * 66;
    int h_in = r0 - 1 + row; h_in = h_in < 0 ? 1 : (h_in > 63 ? 62 : h_in);
    int w_in = pxr - 1;      w_in = w_in < 0 ? 1 : (w_in > 63 ? 62 : w_in);
    int g = ((b * 64 + h_in) * 64 + w_in) * 512 + (t ^ (pxr & 7)) * 8;
    if (i < 4) gx[i] = g; else gxt = g;
  }
  // W staging source offsets (pre-swizzled: physical chunk p holds logical j)
  int gw[4];
  #pragma unroll
  for (int i = 0; i < 4; ++i) {
    int p = tid + i * 512;
    int j = p ^ ((p >> 3) & 7);
    gw[i] = j * 8;
  }

#define STAGE_X(dst, cb_)                                                      \
  do {                                                                         \
    _Pragma("unroll") for (int i = 0; i < 4; ++i)                              \
        gload16(xcat + gx[i] + (cb_) * 64, (dst) + (size_t)(tid + i * 512) * 8); \
    if (wave == 0) gload16(xcat + gxt + (cb_) * 64, (dst) + (size_t)(2048 + lane) * 8); \
  } while (0)

#define STAGE_W(dst, slab)                                                     \
  do {                                                                         \
    const u16* wsrc = w3c + (size_t)(slab) * 16384;                            \
    _Pragma("unroll") for (int i = 0; i < 4; ++i)                              \
        gload16(wsrc + gw[i], (dst) + (size_t)(tid + i * 512) * 8);            \
  } while (0)

  f32x4 zero4 = {0.f, 0.f, 0.f, 0.f};
  f32x4 acc[4][4];
  #pragma unroll
  for (int mi = 0; mi < 4; ++mi)
    #pragma unroll
    for (int nj = 0; nj < 4; ++nj) acc[mi][nj] = zero4;

  STAGE_X(xb0, 0);
  STAGE_W(wb0, 0);  // slab = tap*8 + cb = 0
  __syncthreads();

  for (int cb = 0; cb < 8; ++cb) {
    const u16* xcur = (cb & 1) ? xb1 : xb0;
    #pragma unroll
    for (int tap = 0; tap < 9; ++tap) {
      const u16* wcur = ((cb + tap) & 1) ? wb1 : wb0;
      u16* wnxt = ((cb + tap) & 1) ? wb0 : wb1;
      // issue next-phase stages (fly under this phase's compute)
      if (tap < 8) {
        STAGE_W(wnxt, (tap + 1) * 8 + cb);
      } else if (cb < 7) {
        STAGE_W(wnxt, cb + 1);
        STAGE_X((cb & 1) ? xb0 : xb1, cb + 1);
      }
      // compute current phase from LDS
      const int dy = tap / 3, dx = tap % 3;
      #pragma unroll
      for (int ks = 0; ks < 2; ++ks) {
        bf16x8 af[4], bfr[4];
        #pragma unroll
        for (int mi = 0; mi < 4; ++mi) {
          int pp = mi * 16 + lc + dx;
          af[mi] = *(const bf16x8*)(xcur + ((wr + dy) * 66 + pp) * 64 +
                                    (((ks * 4 + lk) ^ (pp & 7)) * 8));
        }
        #pragma unroll
        for (int nj = 0; nj < 4; ++nj) {
          int n = wc * 64 + nj * 16 + lc;
          int j = ks * 1024 + n * 4 + lk;
          int p = j ^ ((j >> 3) & 7);
          bfr[nj] = *(const bf16x8*)(wcur + p * 8);
        }
        #pragma unroll
        for (int mi = 0; mi < 4; ++mi)
          #pragma unroll
          for (int nj = 0; nj < 4; ++nj)
            acc[mi][nj] = __builtin_amdgcn_mfma_f32_16x16x32_bf16(
                af[mi], bfr[nj], acc[mi][nj], 0, 0, 0);
      }
      __syncthreads();  // drains this phase's stage (vmcnt) + protects buffers
    }
  }
#undef STAGE_X
#undef STAGE_W

  // epilogue: bias + ELU + store
  size_t rowbase = (size_t)((b * 64 + r0 + wr) * 64);
  #pragma unroll
  for (int nj = 0; nj < 4; ++nj) {
    int o = wc * 64 + nj * 16 + lc;
    float bias = b3[o];
    #pragma unroll
    for (int mi = 0; mi < 4; ++mi)
      #pragma unroll
      for (int j = 0; j < 4; ++j) {
        int w = mi * 16 + lk * 4 + j;
        float v = acc[mi][nj][j] + bias;
        v = v > 0.f ? v : (__expf(v) - 1.f);  // ELU
        elux[(rowbase + w) * 256 + o] = f2bf(v);
      }
  }
}

// ---------------- pass 3: final 1x1 conv -> f32 NCHW ----------------
__global__ __launch_bounds__(256, 3) void final_kernel(
    const u16* __restrict__ elux, const u16* __restrict__ w1b,
    const float* __restrict__ b1, float* __restrict__ out) {
  __shared__ __align__(16) u16 at[64 * 256];
  int tid = threadIdx.x;
  int lane = tid & 63, wv_ = tid >> 6;
  int lc = lane & 15, lk = lane >> 4;
  int px0 = blockIdx.x * 64;
  #pragma unroll
  for (int i = 0; i < 8; ++i) {
    int idx = tid + 256 * i;
    int px = idx >> 5, c = idx & 31;
    *(uint4*)(at + px * 256 + (c ^ (px & 7)) * 8) =
        *(const uint4*)(elux + (size_t)(px0 + px) * 256 + c * 8);
  }
  __syncthreads();
  f32x4 zero4 = {0.f, 0.f, 0.f, 0.f};
  f32x4 acc[4][4];
  #pragma unroll
  for (int mi = 0; mi < 4; ++mi)
    #pragma unroll
    for (int nj = 0; nj < 4; ++nj) acc[mi][nj] = zero4;
  gemm_k256(at, w1b, acc, lc, lk, wv_);
  int b = px0 >> 12;
  int hw0 = px0 & 4095;
  #pragma unroll
  for (int nj = 0; nj < 4; ++nj) {
    int o = wv_ * 64 + nj * 16 + lc;
    float bias = b1[o];
    #pragma unroll
    for (int mi = 0; mi < 4; ++mi) {
      float4 v;
      v.x = acc[mi][nj][0] + bias;
      v.y = acc[mi][nj][1] + bias;
      v.z = acc[mi][nj][2] + bias;
      v.w = acc[mi][nj][3] + bias;
      *(float4*)&out[(size_t)(b * 256 + o) * 4096 + hw0 + mi * 16 + lk * 4] = v;
    }
  }
}

extern "C" void kernel_launch(void* const* d_in, const int* in_sizes, int n_in,
                              void* d_out, int out_size, void* d_ws, size_t ws_size,
                              hipStream_t stream) {
  const float* key   = (const float*)d_in[0];
  const float* query = (const float*)d_in[1];
  const float* wq    = (const float*)d_in[2];
  const float* bq    = (const float*)d_in[3];
  const float* wk    = (const float*)d_in[4];
  const float* bk    = (const float*)d_in[5];
  const float* wv    = (const float*)d_in[6];
  const float* bv    = (const float*)d_in[7];
  const float* wW    = (const float*)d_in[8];
  const float* gamma = (const float*)d_in[9];
  const float* beta  = (const float*)d_in[10];
  const float* mean  = (const float*)d_in[11];
  const float* var   = (const float*)d_in[12];
  const float* w3    = (const float*)d_in[13];
  const float* b3    = (const float*)d_in[14];
  const float* w1    = (const float*)d_in[15];
  const float* b1    = (const float*)d_in[16];
  float* out = (float*)d_out;

  char* ws = (char*)d_ws;
  u16* x_q   = (u16*)(ws);                    // 16,777,216 B  [NPX][256] bf16 (query NHWC)
  u16* xcat  = (u16*)(ws + 16777216);         // 33,554,432 B  [NPX][512] bf16 (key | attn out)
  u16* elux  = (u16*)(ws + 50331648);         // 16,777,216 B  [NPX][256] bf16
  u16* w3t   = (u16*)(ws + 67108864);         //  2,359,296 B  [9*8 slabs][2][256][32] bf16
  u16* wqb   = (u16*)(ws + 69468160);         //    131,072 B
  u16* wkb   = (u16*)(ws + 69599232);
  u16* wvb   = (u16*)(ws + 69730304);
  u16* w1b   = (u16*)(ws + 69861376);
  u16* wWpb  = (u16*)(ws + 69992448);         //     32,768 B
  float* bWp = (float*)(ws + 70025216);       //      1,024 B

  (void)hipFuncSetAttribute((const void*)conv3_kernel,
                            hipFuncAttributeMaxDynamicSharedMemorySize, 133120);

  prep_small<<<321, 256, 0, stream>>>(wq, wk, wv, w1, wW, gamma, beta, mean, var,
                                      wqb, wkb, wvb, w1b, wWpb, bWp);
  prep_w3t<<<512, 256, 0, stream>>>(w3, w3t);
  transpose_k<<<2048, 256, 0, stream>>>(query, x_q, 256, 0);
  transpose_k<<<2048, 256, 0, stream>>>(key, xcat, 512, 0);
  attn_kernel<<<512, 256, 0, stream>>>(x_q, xcat, wqb, wkb, wvb, bq, bk, bv, wWpb, bWp);
  conv3_kernel<<<256, 512, 133120, stream>>>(xcat, w3t, b3, elux);
  final_kernel<<<512, 256, 0, stream>>>(elux, w1b, b1, out);
}

// Round 7
// 118.071 us; speedup vs baseline: 1.9412x; 1.1535x over previous
//
#include <hip/hip_runtime.h>
#include <hip/hip_bf16.h>

typedef unsigned short u16;
typedef unsigned int u32;
typedef short bf16x8 __attribute__((ext_vector_type(8)));
typedef float f32x4 __attribute__((ext_vector_type(4)));

#define NPX 32768

__device__ __forceinline__ u16 f2bf(float f) {
  union { float f; u32 u; } v; v.f = f;
  return (u16)((v.u + 0x7FFFu + ((v.u >> 16) & 1u)) >> 16);
}

__device__ __forceinline__ void gload16(const u16* g, u16* l) {
  __builtin_amdgcn_global_load_lds(
      (const __attribute__((address_space(1))) void*)g,
      (__attribute__((address_space(3))) void*)l, 16, 0, 0);
}

// Coalesced B-operand layout: dst = kk*8192 + o*32 + lk*8 + e  (c = kk*32+lk*8+e)

// ---------------- prep kernels ----------------
__global__ __launch_bounds__(256) void prep_small(
    const float* __restrict__ wq, const float* __restrict__ wk,
    const float* __restrict__ wv, const float* __restrict__ w1,
    const float* __restrict__ wW, const float* __restrict__ gamma,
    const float* __restrict__ beta, const float* __restrict__ mean,
    const float* __restrict__ var,
    u16* __restrict__ wqb, u16* __restrict__ wkb, u16* __restrict__ wvb,
    u16* __restrict__ w1b, u16* __restrict__ wWpb, float* __restrict__ bWp) {
  int idx = blockIdx.x * 256 + threadIdx.x;
  if (idx < 65536) {
    int o = idx >> 8, c = idx & 255;
    int dst = (c >> 5) * 8192 + o * 32 + ((c >> 3) & 3) * 8 + (c & 7);
    wqb[dst] = f2bf(wq[idx]);
    wkb[dst] = f2bf(wk[idx]);
    wvb[dst] = f2bf(wv[idx]);
    w1b[dst] = f2bf(w1[idx]);
  } else if (idx < 65536 + 16384) {
    int j = idx - 65536;
    int o = j >> 6, c = j & 63;
    float inv = gamma[o] * rsqrtf(var[o] + 1e-5f);
    int dst = (c >> 5) * 8192 + o * 32 + ((c >> 3) & 3) * 8 + (c & 7);
    wWpb[dst] = f2bf(wW[j] * inv);
  } else if (idx < 65536 + 16384 + 256) {
    int o = idx - 65536 - 16384;
    float inv = gamma[o] * rsqrtf(var[o] + 1e-5f);
    bWp[o] = beta[o] - mean[o] * inv;
  }
}

// w3 [o][c][3][3] f32 -> w3c [(t*8+cb)][ks][o][lk][8] bf16 slabs (16384 u16 per (t,cb))
__global__ __launch_bounds__(256) void prep_w3t(const float* __restrict__ w3,
                                                u16* __restrict__ w3c) {
  int idx = blockIdx.x * 256 + threadIdx.x;  // o*512+c, 131072 total
  int o = idx >> 9, c = idx & 511;
  int cb = c >> 6, ks = (c >> 5) & 1, lk = (c >> 3) & 3, e = c & 7;
  #pragma unroll
  for (int t = 0; t < 9; ++t)
    w3c[(size_t)(((t * 8 + cb) * 2 + ks) * 256 + o) * 32 + lk * 8 + e] =
        f2bf(w3[idx * 9 + t]);
}

// ---------------- pass 1: NCHW->NHWC transpose (fused) + QKV + attention + W + BN ----------------
__global__ __launch_bounds__(256, 2) void attn_kernel(
    const float* __restrict__ qsrc, const float* __restrict__ ksrc,
    u16* __restrict__ xcat,
    const u16* __restrict__ wqb, const u16* __restrict__ wkb, const u16* __restrict__ wvb,
    const float* __restrict__ bq, const float* __restrict__ bk, const float* __restrict__ bv,
    const u16* __restrict__ wWpb, const float* __restrict__ bWp) {
  __shared__ __align__(16) char smem[74752];
  u16* aq = (u16*)smem;                    // [64][256] swizzled, 32KB
  u16* ak = (u16*)(smem + 32768);          // [64][256] swizzled, 32KB
  u16* tile = (u16*)(smem + 65536);        // [64][72] transpose tile, 9216B
  float* att_s = (float*)(smem + 65536);   // [4][64] (after tile is dead)
  u16* wsum = (u16*)(smem + 66560);        // [64][64] swizzled, 8KB
  float* wbuf = (float*)smem;              // [4][64][64] f32, reuses aq/ak
  u16* ob = (u16*)smem;                    // [64][264] out stage, reuses aq/ak

  int tid = threadIdx.x;
  int lane = tid & 63, wv_ = tid >> 6;
  int lc = lane & 15, lk = lane >> 4;
  int px0 = blockIdx.x * 64;
  int b = px0 >> 12, hw0 = px0 & 4095;

  // ---- fused transpose: 8 rounds (Q cc=0..3, K cc=0..3) ----
  #pragma unroll
  for (int t = 0; t < 8; ++t) {
    const float* src = (t < 4) ? qsrc : ksrc;
    int cc = t & 3;
    #pragma unroll
    for (int i = 0; i < 4; ++i) {
      int idx = tid + 256 * i;
      int c = idx >> 4, p4 = idx & 15;
      const float4 v = *(const float4*)&src[(size_t)(b * 256 + cc * 64 + c) * 4096 + hw0 + p4 * 4];
      u32 lo = f2bf(v.x) | ((u32)f2bf(v.y) << 16);
      u32 hi = f2bf(v.z) | ((u32)f2bf(v.w) << 16);
      *(uint2*)&tile[c * 72 + p4 * 4] = make_uint2(lo, hi);
    }
    __syncthreads();
    int px = tid >> 2, cq = tid & 3;
    u32 vv[8];
    #pragma unroll
    for (int i = 0; i < 8; ++i) {
      u16 a = tile[(cq * 16 + 2 * i) * 72 + px];
      u16 bb = tile[(cq * 16 + 2 * i + 1) * 72 + px];
      vv[i] = a | ((u32)bb << 16);
    }
    u16* dstl = (t < 4) ? aq : ak;
    int c8 = cc * 8 + cq * 2;
    *(uint4*)(dstl + px * 256 + (c8 ^ (px & 7)) * 8) = make_uint4(vv[0], vv[1], vv[2], vv[3]);
    *(uint4*)(dstl + px * 256 + ((c8 + 1) ^ (px & 7)) * 8) = make_uint4(vv[4], vv[5], vv[6], vv[7]);
    if (t >= 4) {  // key: also write linear bf16 into xcat[px][0..255]
      u16* dp = xcat + (size_t)(px0 + px) * 512 + cc * 64 + cq * 16;
      *(uint4*)dp = make_uint4(vv[0], vv[1], vv[2], vv[3]);
      *(uint4*)(dp + 8) = make_uint4(vv[4], vv[5], vv[6], vv[7]);
    }
    __syncthreads();
  }

  f32x4 zero4 = {0.f, 0.f, 0.f, 0.f};
  f32x4 accq[4][4], acck[4][4];
  #pragma unroll
  for (int mi = 0; mi < 4; ++mi)
    #pragma unroll
    for (int nj = 0; nj < 4; ++nj) { accq[mi][nj] = zero4; acck[mi][nj] = zero4; }

  // Q = aq x wqb, K = ak x wkb  (K=256, B coalesced: kk*8192 + n*32 + lk*8)
  #pragma unroll
  for (int kk = 0; kk < 8; ++kk) {
    bf16x8 afq[4], afk[4], bfq[4], bfk[4];
    #pragma unroll
    for (int mi = 0; mi < 4; ++mi) {
      int px = mi * 16 + lc;
      int s = (kk * 4 + lk) ^ (px & 7);
      afq[mi] = *(const bf16x8*)(aq + px * 256 + s * 8);
      afk[mi] = *(const bf16x8*)(ak + px * 256 + s * 8);
    }
    #pragma unroll
    for (int nj = 0; nj < 4; ++nj) {
      int n = wv_ * 64 + nj * 16 + lc;
      bfq[nj] = *(const bf16x8*)(wqb + kk * 8192 + n * 32 + lk * 8);
      bfk[nj] = *(const bf16x8*)(wkb + kk * 8192 + n * 32 + lk * 8);
    }
    #pragma unroll
    for (int mi = 0; mi < 4; ++mi)
      #pragma unroll
      for (int nj = 0; nj < 4; ++nj) {
        accq[mi][nj] = __builtin_amdgcn_mfma_f32_16x16x32_bf16(afq[mi], bfq[nj], accq[mi][nj], 0, 0, 0);
        acck[mi][nj] = __builtin_amdgcn_mfma_f32_16x16x32_bf16(afk[mi], bfk[nj], acck[mi][nj], 0, 0, 0);
      }
  }

  #pragma unroll
  for (int nj = 0; nj < 4; ++nj) {
    float bqv = bq[wv_ * 64 + nj * 16 + lc];
    float bkv = bk[wv_ * 64 + nj * 16 + lc];
    #pragma unroll
    for (int mi = 0; mi < 4; ++mi)
      #pragma unroll
      for (int j = 0; j < 4; ++j) { accq[mi][nj][j] += bqv; acck[mi][nj][j] += bkv; }
  }

  // attention scores for own head (wave == head); reduce over the 16 col-lanes
  float smx[4][4];
  #pragma unroll
  for (int mi = 0; mi < 4; ++mi)
    #pragma unroll
    for (int j = 0; j < 4; ++j) {
      float p = 0.f;
      #pragma unroll
      for (int nj = 0; nj < 4; ++nj) p += accq[mi][nj][j] * acck[mi][nj][j];
      p += __shfl_xor(p, 1);
      p += __shfl_xor(p, 2);
      p += __shfl_xor(p, 4);
      p += __shfl_xor(p, 8);
      float a = p * 0.0625f;  // / sqrt(256)
      smx[mi][j] = a;
      if (lc == 0) att_s[wv_ * 64 + mi * 16 + lk * 4 + j] = a;
    }
  __syncthreads();
  // softmax over 4 heads
  #pragma unroll
  for (int mi = 0; mi < 4; ++mi)
    #pragma unroll
    for (int j = 0; j < 4; ++j) {
      int px = mi * 16 + lk * 4 + j;
      float a0 = att_s[px], a1 = att_s[64 + px], a2 = att_s[128 + px], a3 = att_s[192 + px];
      float mx = fmaxf(fmaxf(a0, a1), fmaxf(a2, a3));
      float e0 = __expf(a0 - mx), e1 = __expf(a1 - mx);
      float e2 = __expf(a2 - mx), e3 = __expf(a3 - mx);
      float den = e0 + e1 + e2 + e3;
      float ew = wv_ == 0 ? e0 : (wv_ == 1 ? e1 : (wv_ == 2 ? e2 : e3));
      smx[mi][j] = ew / den;
    }

  // V projection
  f32x4 accv[4][4];
  #pragma unroll
  for (int mi = 0; mi < 4; ++mi)
    #pragma unroll
    for (int nj = 0; nj < 4; ++nj) accv[mi][nj] = zero4;
  #pragma unroll
  for (int kk = 0; kk < 8; ++kk) {
    bf16x8 af[4], bfr[4];
    #pragma unroll
    for (int mi = 0; mi < 4; ++mi) {
      int px = mi * 16 + lc;
      int s = (kk * 4 + lk) ^ (px & 7);
      af[mi] = *(const bf16x8*)(ak + px * 256 + s * 8);
    }
    #pragma unroll
    for (int nj = 0; nj < 4; ++nj) {
      int n = wv_ * 64 + nj * 16 + lc;
      bfr[nj] = *(const bf16x8*)(wvb + kk * 8192 + n * 32 + lk * 8);
    }
    #pragma unroll
    for (int mi = 0; mi < 4; ++mi)
      #pragma unroll
      for (int nj = 0; nj < 4; ++nj)
        accv[mi][nj] = __builtin_amdgcn_mfma_f32_16x16x32_bf16(af[mi], bfr[nj], accv[mi][nj], 0, 0, 0);
  }
  #pragma unroll
  for (int nj = 0; nj < 4; ++nj) {
    float bvv = bv[wv_ * 64 + nj * 16 + lc];
    #pragma unroll
    for (int mi = 0; mi < 4; ++mi)
      #pragma unroll
      for (int j = 0; j < 4; ++j) accv[mi][nj][j] += bvv;
  }
  __syncthreads();  // all waves done reading aq/ak -> reuse as wbuf

  #pragma unroll
  for (int mi = 0; mi < 4; ++mi)
    #pragma unroll
    for (int nj = 0; nj < 4; ++nj)
      #pragma unroll
      for (int j = 0; j < 4; ++j) {
        int px = mi * 16 + lk * 4 + j;
        wbuf[(wv_ * 64 + px) * 64 + nj * 16 + lc] = smx[mi][j] * accv[mi][nj][j];
      }
  __syncthreads();

  // sum heads -> weighted [64px][64d] bf16 (swizzled)
  #pragma unroll
  for (int i = 0; i < 2; ++i) {
    int idx = tid + 256 * i;
    int px = idx >> 3, c = idx & 7;
    float a8[8] = {0.f, 0.f, 0.f, 0.f, 0.f, 0.f, 0.f, 0.f};
    #pragma unroll
    for (int h = 0; h < 4; ++h) {
      const float4* p = (const float4*)(wbuf + ((h * 64 + px) * 64 + c * 8));
      float4 u0 = p[0], u1 = p[1];
      a8[0] += u0.x; a8[1] += u0.y; a8[2] += u0.z; a8[3] += u0.w;
      a8[4] += u1.x; a8[5] += u1.y; a8[6] += u1.z; a8[7] += u1.w;
    }
    u32 p0 = f2bf(a8[0]) | ((u32)f2bf(a8[1]) << 16);
    u32 p1 = f2bf(a8[2]) | ((u32)f2bf(a8[3]) << 16);
    u32 p2 = f2bf(a8[4]) | ((u32)f2bf(a8[5]) << 16);
    u32 p3 = f2bf(a8[6]) | ((u32)f2bf(a8[7]) << 16);
    *(uint4*)(wsum + px * 64 + (c ^ (px & 7)) * 8) = make_uint4(p0, p1, p2, p3);
  }
  __syncthreads();

  // out = weighted x wW'^T + bWp  (K=64)
  f32x4 a4[4][4];
  #pragma unroll
  for (int mi = 0; mi < 4; ++mi)
    #pragma unroll
    for (int nj = 0; nj < 4; ++nj) a4[mi][nj] = zero4;
  #pragma unroll
  for (int kk = 0; kk < 2; ++kk) {
    bf16x8 af[4], bfr[4];
    #pragma unroll
    for (int mi = 0; mi < 4; ++mi) {
      int px = mi * 16 + lc;
      int s = (kk * 4 + lk) ^ (px & 7);
      af[mi] = *(const bf16x8*)(wsum + px * 64 + s * 8);
    }
    #pragma unroll
    for (int nj = 0; nj < 4; ++nj) {
      int n = wv_ * 64 + nj * 16 + lc;
      bfr[nj] = *(const bf16x8*)(wWpb + kk * 8192 + n * 32 + lk * 8);
    }
    #pragma unroll
    for (int mi = 0; mi < 4; ++mi)
      #pragma unroll
      for (int nj = 0; nj < 4; ++nj)
        a4[mi][nj] = __builtin_amdgcn_mfma_f32_16x16x32_bf16(af[mi], bfr[nj], a4[mi][nj], 0, 0, 0);
  }
  // stage out through LDS (ob, [64][264]) then coalesced 16B stores
  #pragma unroll
  for (int nj = 0; nj < 4; ++nj) {
    int o = wv_ * 64 + nj * 16 + lc;
    float bb = bWp[o];
    #pragma unroll
    for (int mi = 0; mi < 4; ++mi)
      #pragma unroll
      for (int j = 0; j < 4; ++j) {
        int px = mi * 16 + lk * 4 + j;
        ob[px * 264 + o] = f2bf(a4[mi][nj][j] + bb);
      }
  }
  __syncthreads();
  #pragma unroll
  for (int i = 0; i < 8; ++i) {
    int idx = tid + 256 * i;
    int px = idx >> 5, c8 = idx & 31;
    *(uint4*)(xcat + (size_t)(px0 + px) * 512 + 256 + c8 * 8) =
        *(const uint4*)(ob + px * 264 + c8 * 8);
  }
}

// ---------------- pass 2: reflect-pad 3x3 conv (512->256) + ELU + fused final 1x1 ----------------
// Canonical 2-phase LDS GEMM: M=128 (2 rows), N=256, 72 phases of K=64.
// BOTH conv operands via global_load_lds, double-buffered; grid 256 = 1 block/CU,
// 8 waves 2Mx4N. After the conv loop: ELU -> LDS [128][264] -> fused 1x1 (K=256)
// with w1b streamed coalesced from L2 -> f32 NCHW float4 stores.
__global__ __launch_bounds__(512, 2) void conv3_kernel(
    const u16* __restrict__ xcat, const u16* __restrict__ w3c,
    const float* __restrict__ b3, const u16* __restrict__ w1b,
    const float* __restrict__ b1, float* __restrict__ out) {
  extern __shared__ __align__(16) u16 smem[];
  u16* xb0 = smem;              // [4][66][64] = 16896 u16
  u16* xb1 = smem + 16896;
  u16* wb0 = smem + 33792;      // [2ks][256n][32] = 16384 u16
  u16* wb1 = smem + 50176;      // total 66560 u16 = 133120 B

  int tid = threadIdx.x;
  int lane = tid & 63, wave = tid >> 6;
  int lc = lane & 15, lk = lane >> 4;
  int wr = wave >> 2, wc = wave & 3;
  int b = blockIdx.x >> 5, r0 = (blockIdx.x & 31) * 2;

  // x staging source offsets: 2112 chunks = 4 rows x 66 px x 8; 4/thread + 64 tail
  int gx[4], gxt;
  #pragma unroll
  for (int i = 0; i < 5; ++i) {
    int idx = (i < 4) ? (tid + i * 512) : (2048 + lane);
    int px = idx >> 3, t = idx & 7;
    int row = px / 66;
    int pxr = px - row * 66;
    int h_in = r0 - 1 + row; h_in = h_in < 0 ? 1 : (h_in > 63 ? 62 : h_in);
    int w_in = pxr - 1;      w_in = w_in < 0 ? 1 : (w_in > 63 ? 62 : w_in);
    int g = ((b * 64 + h_in) * 64 + w_in) * 512 + (t ^ (pxr & 7)) * 8;
    if (i < 4) gx[i] = g; else gxt = g;
  }
  // W staging source offsets (pre-swizzled: physical chunk p holds logical j)
  int gw[4];
  #pragma unroll
  for (int i = 0; i < 4; ++i) {
    int p = tid + i * 512;
    int j = p ^ ((p >> 3) & 7);
    gw[i] = j * 8;
  }

#define STAGE_X(dst, cb_)                                                      \
  do {                                                                         \
    _Pragma("unroll") for (int i = 0; i < 4; ++i)                              \
        gload16(xcat + gx[i] + (cb_) * 64, (dst) + (size_t)(tid + i * 512) * 8); \
    if (wave == 0) gload16(xcat + gxt + (cb_) * 64, (dst) + (size_t)(2048 + lane) * 8); \
  } while (0)

#define STAGE_W(dst, slab)                                                     \
  do {                                                                         \
    const u16* wsrc = w3c + (size_t)(slab) * 16384;                            \
    _Pragma("unroll") for (int i = 0; i < 4; ++i)                              \
        gload16(wsrc + gw[i], (dst) + (size_t)(tid + i * 512) * 8);            \
  } while (0)

  f32x4 zero4 = {0.f, 0.f, 0.f, 0.f};
  f32x4 acc[4][4];
  #pragma unroll
  for (int mi = 0; mi < 4; ++mi)
    #pragma unroll
    for (int nj = 0; nj < 4; ++nj) acc[mi][nj] = zero4;

  STAGE_X(xb0, 0);
  STAGE_W(wb0, 0);  // slab = tap*8 + cb = 0
  __syncthreads();

  for (int cb = 0; cb < 8; ++cb) {
    const u16* xcur = (cb & 1) ? xb1 : xb0;
    #pragma unroll
    for (int tap = 0; tap < 9; ++tap) {
      const u16* wcur = ((cb + tap) & 1) ? wb1 : wb0;
      u16* wnxt = ((cb + tap) & 1) ? wb0 : wb1;
      // issue next-phase stages (fly under this phase's compute)
      if (tap < 8) {
        STAGE_W(wnxt, (tap + 1) * 8 + cb);
      } else if (cb < 7) {
        STAGE_W(wnxt, cb + 1);
        STAGE_X((cb & 1) ? xb0 : xb1, cb + 1);
      }
      // compute current phase from LDS
      const int dy = tap / 3, dx = tap % 3;
      #pragma unroll
      for (int ks = 0; ks < 2; ++ks) {
        bf16x8 af[4], bfr[4];
        #pragma unroll
        for (int mi = 0; mi < 4; ++mi) {
          int pp = mi * 16 + lc + dx;
          af[mi] = *(const bf16x8*)(xcur + ((wr + dy) * 66 + pp) * 64 +
                                    (((ks * 4 + lk) ^ (pp & 7)) * 8));
        }
        #pragma unroll
        for (int nj = 0; nj < 4; ++nj) {
          int n = wc * 64 + nj * 16 + lc;
          int j = ks * 1024 + n * 4 + lk;
          int p = j ^ ((j >> 3) & 7);
          bfr[nj] = *(const bf16x8*)(wcur + p * 8);
        }
        __builtin_amdgcn_s_setprio(1);
        #pragma unroll
        for (int mi = 0; mi < 4; ++mi)
          #pragma unroll
          for (int nj = 0; nj < 4; ++nj)
            acc[mi][nj] = __builtin_amdgcn_mfma_f32_16x16x32_bf16(
                af[mi], bfr[nj], acc[mi][nj], 0, 0, 0);
        __builtin_amdgcn_s_setprio(0);
      }
      __syncthreads();  // drains this phase's stage (vmcnt) + protects buffers
    }
  }
#undef STAGE_X
#undef STAGE_W

  // ===== epilogue: bias + ELU -> LDS [128][264], then fused final 1x1 (K=256) =====
  u16* eb = smem;
  #pragma unroll
  for (int nj = 0; nj < 4; ++nj) {
    int o = wc * 64 + nj * 16 + lc;
    float bias = b3[o];
    #pragma unroll
    for (int mi = 0; mi < 4; ++mi)
      #pragma unroll
      for (int j = 0; j < 4; ++j) {
        int p = wr * 64 + mi * 16 + lk * 4 + j;
        float v = acc[mi][nj][j] + bias;
        v = v > 0.f ? v : (__expf(v) - 1.f);  // ELU
        eb[p * 264 + o] = f2bf(v);
      }
  }
  __syncthreads();

  f32x4 acc2[4][4];
  #pragma unroll
  for (int mi = 0; mi < 4; ++mi)
    #pragma unroll
    for (int nj = 0; nj < 4; ++nj) acc2[mi][nj] = zero4;
  #pragma unroll
  for (int kk = 0; kk < 8; ++kk) {
    bf16x8 af[4], bfr[4];
    #pragma unroll
    for (int mi = 0; mi < 4; ++mi)
      af[mi] = *(const bf16x8*)(eb + (wr * 64 + mi * 16 + lc) * 264 + kk * 32 + lk * 8);
    #pragma unroll
    for (int nj = 0; nj < 4; ++nj)
      bfr[nj] = *(const bf16x8*)(w1b + kk * 8192 + (wc * 64 + nj * 16 + lc) * 32 + lk * 8);
    #pragma unroll
    for (int mi = 0; mi < 4; ++mi)
      #pragma unroll
      for (int nj = 0; nj < 4; ++nj)
        acc2[mi][nj] = __builtin_amdgcn_mfma_f32_16x16x32_bf16(af[mi], bfr[nj], acc2[mi][nj], 0, 0, 0);
  }
  // write f32 NCHW: wave wr owns row r0+wr
  #pragma unroll
  for (int nj = 0; nj < 4; ++nj) {
    int o = wc * 64 + nj * 16 + lc;
    float bias = b1[o];
    #pragma unroll
    for (int mi = 0; mi < 4; ++mi) {
      float4 v;
      v.x = acc2[mi][nj][0] + bias;
      v.y = acc2[mi][nj][1] + bias;
      v.z = acc2[mi][nj][2] + bias;
      v.w = acc2[mi][nj][3] + bias;
      *(float4*)&out[(size_t)(b * 256 + o) * 4096 + (r0 + wr) * 64 + mi * 16 + lk * 4] = v;
    }
  }
}

extern "C" void kernel_launch(void* const* d_in, const int* in_sizes, int n_in,
                              void* d_out, int out_size, void* d_ws, size_t ws_size,
                              hipStream_t stream) {
  const float* key   = (const float*)d_in[0];
  const float* query = (const float*)d_in[1];
  const float* wq    = (const float*)d_in[2];
  const float* bq    = (const float*)d_in[3];
  const float* wk    = (const float*)d_in[4];
  const float* bk    = (const float*)d_in[5];
  const float* wv    = (const float*)d_in[6];
  const float* bv    = (const float*)d_in[7];
  const float* wW    = (const float*)d_in[8];
  const float* gamma = (const float*)d_in[9];
  const float* beta  = (const float*)d_in[10];
  const float* mean  = (const float*)d_in[11];
  const float* var   = (const float*)d_in[12];
  const float* w3    = (const float*)d_in[13];
  const float* b3    = (const float*)d_in[14];
  const float* w1    = (const float*)d_in[15];
  const float* b1    = (const float*)d_in[16];
  float* out = (float*)d_out;

  char* ws = (char*)d_ws;
  u16* xcat  = (u16*)(ws + 16777216);         // 33,554,432 B  [NPX][512] bf16 (key | attn out)
  u16* w3t   = (u16*)(ws + 67108864);         //  2,359,296 B  [9*8 slabs][2][256][32] bf16
  u16* wqb   = (u16*)(ws + 69468160);         //    131,072 B
  u16* wkb   = (u16*)(ws + 69599232);
  u16* wvb   = (u16*)(ws + 69730304);
  u16* w1b   = (u16*)(ws + 69861376);
  u16* wWpb  = (u16*)(ws + 69992448);         //     32,768 B
  float* bWp = (float*)(ws + 70025216);       //      1,024 B

  (void)hipFuncSetAttribute((const void*)conv3_kernel,
                            hipFuncAttributeMaxDynamicSharedMemorySize, 133120);

  prep_small<<<321, 256, 0, stream>>>(wq, wk, wv, w1, wW, gamma, beta, mean, var,
                                      wqb, wkb, wvb, w1b, wWpb, bWp);
  prep_w3t<<<512, 256, 0, stream>>>(w3, w3t);
  attn_kernel<<<512, 256, 0, stream>>>(query, key, xcat, wqb, wkb, wvb,
                                       bq, bk, bv, wWpb, bWp);
  conv3_kernel<<<256, 512, 133120, stream>>>(xcat, w3t, b3, w1b, b1, out);
}